// Round 10
// baseline (127.110 us; speedup 1.0000x reference)
//
#include <hip/hip_runtime.h>
#include <hip/hip_bf16.h>
#include <stdint.h>

#define B_SZ 1024
#define M_SZ 209
#define MPAD 224            // padded M rows (14 * 16)
#define NTILE 14            // 16-wide col tiles total
#define D_SZ 12288
#define KC   32             // split-K chunks
#define KCH  384            // K elems per chunk (D/KC)
#define KG   12             // 32-wide k-steps per chunk (KCH/32)
#define KGTOT (D_SZ / 32)   // 384 global k-steps
#define NB   32             // B splits -> grid (32,32) = 1024 blocks = 4/CU
#define BT   32             // B rows per block
#define NCT  7              // 16-wide col tiles per wave (ct-half)
#define SROW 224            // slab k-stride (bf16 elems)
#define SLROW (KC * SROW)   // 7168

// cT: B-fragment-ordered c, fp8: [kg_global][ct][lane*8B] = 384*14*512 B
#define CT_OFF   0u                                   // 2.75 MB
#define XXP_OFF  (KGTOT * NTILE * 512)                // xx partials [B][KC] f32
#define CC_OFF   (XXP_OFF + B_SZ * KC * 4)            // cc [224] f32
#define SLAB_OFF (CC_OFF + 1024)                      // slab [B][KC][224] bf16 (14.7 MB)

typedef __attribute__((ext_vector_type(8))) short short8;
typedef __attribute__((ext_vector_type(4))) float floatx4;

__device__ __forceinline__ uint32_t pk8x4(const float4& v) {
    int d = __builtin_amdgcn_cvt_pk_fp8_f32(v.x, v.y, 0, false);
    d     = __builtin_amdgcn_cvt_pk_fp8_f32(v.z, v.w, d, true);
    return (uint32_t)d;
}

__device__ __forceinline__ float bfbits2f(unsigned short u) {
    union { uint32_t u; float f; } cv;
    cv.u = ((uint32_t)u) << 16;
    return cv.f;
}

// ---------------------------------------------------------------------------
// prepass: c fp32 -> fp8, permuted into MFMA B-fragment order, + ||c||^2.
// One block per padded row j. Fragment law (16x16x32): lane (q,mrow) holds
// B[col j = mrow][k = q*8 + i] -> byte offset in 512B block = q*128 + mrow*8.
__global__ __launch_bounds__(256) void rbf_prep(
    const float* __restrict__ c, uint8_t* __restrict__ cT,
    float* __restrict__ cc)
{
    __shared__ float red[4];
    const int j = blockIdx.x, t = threadIdx.x;
    const int ct = j >> 4, mrow = j & 15;
    float s = 0.f;
    for (int kg = t; kg < KGTOT; kg += 256) {
        uint8_t* dst = cT + ((size_t)kg * NTILE + ct) * 512 + mrow * 8;
        if (j < M_SZ) {
            const float* src = c + (size_t)j * D_SZ + kg * 32;
#pragma unroll
            for (int q = 0; q < 4; ++q) {
                float4 a = *(const float4*)(src + q * 8);
                float4 b = *(const float4*)(src + q * 8 + 4);
                s += a.x*a.x + a.y*a.y + a.z*a.z + a.w*a.w
                   + b.x*b.x + b.y*b.y + b.z*b.z + b.w*b.w;
                uint2 w = { pk8x4(a), pk8x4(b) };
                *(uint2*)(dst + q * 128) = w;
            }
        } else {
            const uint2 z = {0u, 0u};
#pragma unroll
            for (int q = 0; q < 4; ++q) *(uint2*)(dst + q * 128) = z;
        }
    }
#pragma unroll
    for (int off = 32; off > 0; off >>= 1) s += __shfl_down(s, off);
    if ((t & 63) == 0) red[t >> 6] = s;
    __syncthreads();
    if (t == 0) cc[j] = red[0] + red[1] + red[2] + red[3];
}

// ---------------------------------------------------------------------------
// main: split-K distance GEMM, 16x16x32 fp8_fp8 MFMA.
// ZERO LDS, ZERO barriers. A (x rows) packed to fp8 in registers (R8 law);
// B streamed from fragment-ordered cT as coalesced 512B global loads,
// 2-stage register pipeline so loads overlap MFMA (vmcnt-style).
__global__ __launch_bounds__(256, 4) void rbf_main(
    const float* __restrict__ x, const uint8_t* __restrict__ cT,
    __hip_bfloat16* __restrict__ slab, float* __restrict__ xxp)
{
    const int t    = threadIdx.x;
    const int k    = blockIdx.x;
    const int b    = blockIdx.y;
    const int wave = t >> 6, lane = t & 63;
    const int quad = lane >> 4, mrow = lane & 15;
    const int rt   = wave & 1;          // row-tile (16 x-rows)
    const int cth  = wave >> 1;         // ct-half (7 tiles)

    floatx4 acc[NCT];
    const floatx4 z4 = {0.f, 0.f, 0.f, 0.f};
#pragma unroll
    for (int i = 0; i < NCT; ++i) acc[i] = z4;

    // ---- A prefetch: this lane's x row slice -> 12 fp8-longs + ||x||^2 part
    const float* xr = x + (size_t)(b * BT + rt * 16 + mrow) * D_SZ
                    + (size_t)k * KCH + quad * 8;
    long xa[KG];
    float sxx = 0.f;
#pragma unroll
    for (int kg = 0; kg < KG; ++kg) {
        float4 a = *(const float4*)(xr + kg * 32);
        float4 bv = *(const float4*)(xr + kg * 32 + 4);
        sxx += a.x*a.x + a.y*a.y + a.z*a.z + a.w*a.w
             + bv.x*bv.x + bv.y*bv.y + bv.z*bv.z + bv.w*bv.w;
        const uint32_t lo = pk8x4(a);
        const uint32_t hi = pk8x4(bv);
        xa[kg] = (long)(((uint64_t)hi << 32) | lo);
    }

    // ---- B streaming: fragment base for (k, cth), advance 14*512 B per kg
    const uint8_t* bp = cT + ((size_t)(k * KG) * NTILE + cth * NCT) * 512 + lane * 8;

    long bf[2][NCT];
#pragma unroll
    for (int ct = 0; ct < NCT; ++ct)
        bf[0][ct] = *(const long*)(bp + ct * 512);

#pragma unroll
    for (int kg = 0; kg < KG; ++kg) {
        const int cur = kg & 1, nxt = cur ^ 1;
        if (kg + 1 < KG) {
            const uint8_t* np = bp + (size_t)(kg + 1) * NTILE * 512;
#pragma unroll
            for (int ct = 0; ct < NCT; ++ct)
                bf[nxt][ct] = *(const long*)(np + ct * 512);
        }
        const long a = xa[kg];
#pragma unroll
        for (int ct = 0; ct < NCT; ++ct)
            acc[ct] = __builtin_amdgcn_mfma_f32_16x16x32_fp8_fp8(a, bf[cur][ct], acc[ct], 0, 0, 0);
    }

    // ---- slab write: [i][k][224] bf16. C/D: col=lane&15, row=quad*4+reg
    __hip_bfloat16* sd = slab + (size_t)k * SROW;
    const int gi0 = b * BT + rt * 16 + quad * 4;
#pragma unroll
    for (int ct = 0; ct < NCT; ++ct) {
        const int gj = (cth * NCT + ct) * 16 + mrow;
#pragma unroll
        for (int rg = 0; rg < 4; ++rg)
            sd[(size_t)(gi0 + rg) * SLROW + gj] = __float2bfloat16(acc[ct][rg]);
    }

    // ---- xx partials: reduce over quads (cth==0 waves only; no atomics)
    sxx += __shfl_down(sxx, 32);
    sxx += __shfl_down(sxx, 16);
    if (cth == 0 && lane < 16)
        xxp[(size_t)(b * BT + rt * 16 + lane) * KC + k] = sxx;
}

// ---------------------------------------------------------------------------
// finalize: one block per row; octet k-reduction of bf16 slab, then radial
// + W epilogue.
__global__ __launch_bounds__(256) void rbf_fin(
    const __hip_bfloat16* __restrict__ slab, const float* __restrict__ xxp,
    const float* __restrict__ cc, const float* __restrict__ sigma,
    const float* __restrict__ W, const float* __restrict__ bias,
    float* __restrict__ out)
{
    __shared__ float jpart[MPAD * 9];
    __shared__ float jtot[MPAD];
    __shared__ float xsh;

    const int t = threadIdx.x;
    const int i = blockIdx.x;

    if (t < 64) {
        float xv = (t < KC) ? xxp[(size_t)i * KC + t] : 0.f;
#pragma unroll
        for (int off = 32; off > 0; off >>= 1) xv += __shfl_down(xv, off);
        if (t == 0) xsh = xv;
    }

    const int o = t % 28, g = t / 28;
    if (t < 252) {
        const unsigned short* sp = (const unsigned short*)slab
                                 + (size_t)i * SLROW + o * 8;
        float s8[8] = {0.f,0.f,0.f,0.f,0.f,0.f,0.f,0.f};
        for (int kk = g; kk < KC; kk += 9) {
            short8 v = *(const short8*)(sp + kk * SROW);
#pragma unroll
            for (int e = 0; e < 8; ++e) s8[e] += bfbits2f((unsigned short)v[e]);
        }
#pragma unroll
        for (int e = 0; e < 8; ++e) jpart[(o * 8 + e) * 9 + g] = s8[e];
    }
    __syncthreads();

    if (t < MPAD) {
        float d = 0.f;
#pragma unroll
        for (int g2 = 0; g2 < 9; ++g2) d += jpart[t * 9 + g2];
        jtot[t] = d;
    }
    __syncthreads();

    if (t < 64) {
        const float xxi = xsh;
        float a0 = 0.f, a1 = 0.f;
        for (int j = t; j < M_SZ; j += 64) {
            float d2 = fmaxf(xxi + cc[j] - 2.f * jtot[j], 0.f);
            float sg = sigma[j];
            float rad = __expf(-sqrtf(d2) / (sg * sg));
            a0 += rad * W[j];
            a1 += rad * W[M_SZ + j];
        }
#pragma unroll
        for (int off = 32; off > 0; off >>= 1) {
            a0 += __shfl_down(a0, off);
            a1 += __shfl_down(a1, off);
        }
        if (t == 0) {
            out[i * 2 + 0] = a0 + bias[0];
            out[i * 2 + 1] = a1 + bias[1];
        }
    }
}

// ---------------------------------------------------------------------------
extern "C" void kernel_launch(void* const* d_in, const int* in_sizes, int n_in,
                              void* d_out, int out_size, void* d_ws, size_t ws_size,
                              hipStream_t stream)
{
    const float* x     = (const float*)d_in[0];
    const float* c     = (const float*)d_in[1];
    const float* sigma = (const float*)d_in[2];
    const float* W     = (const float*)d_in[3];
    const float* bias  = (const float*)d_in[4];
    float* out = (float*)d_out;

    char* ws = (char*)d_ws;
    uint8_t*        cT   = (uint8_t*)(ws + CT_OFF);
    float*          xxp  = (float*)(ws + XXP_OFF);
    float*          cc   = (float*)(ws + CC_OFF);
    __hip_bfloat16* slab = (__hip_bfloat16*)(ws + SLAB_OFF);

    rbf_prep<<<MPAD, 256, 0, stream>>>(c, cT, cc);
    rbf_main<<<dim3(KC, NB), 256, 0, stream>>>(x, cT, slab, xxp);
    rbf_fin<<<B_SZ, 256, 0, stream>>>(slab, xxp, cc, sigma, W, bias, out);
}

// Round 11
// 110.478 us; speedup vs baseline: 1.1506x; 1.1506x over previous
//
#include <hip/hip_runtime.h>
#include <hip/hip_bf16.h>
#include <stdint.h>

#define B_SZ 1024
#define M_SZ 209
#define MPAD 224            // padded M rows (14 * 16)
#define D_SZ 12288
#define KC   32             // split-K chunks
#define KCH  384            // K elems per chunk (D/KC)
#define BK   128            // K per staging iteration (fp8 bytes == elems)
#define NIT  (KCH / BK)     // 3
#define NB   32             // B splits -> grid (32,32) = 1024 blocks = 4/CU
#define BT   32             // B rows per block
#define NCT  7              // 16-wide col tiles per wave (ct-half)
#define SROW 224            // slab k-stride (bf16 elems)
#define SLROW (KC * SROW)   // 7168

// ws byte offsets
#define CBF_OFF  0u                                   // c fp8 [224][12288] (2.75 MB)
#define XXP_OFF  (MPAD * D_SZ)                        // xx partials [B][KC] f32
#define CCP_OFF  (XXP_OFF + B_SZ * KC * 4)            // cc halves [224][2] f32
#define SLAB_OFF (CCP_OFF + MPAD * 2 * 4)             // slab [B][KC][224] bf16 (14.7 MB)

typedef __attribute__((ext_vector_type(8))) short short8;
typedef __attribute__((ext_vector_type(4))) float floatx4;

__device__ __forceinline__ uint32_t pk8x4(const float4& v) {
    int d = __builtin_amdgcn_cvt_pk_fp8_f32(v.x, v.y, 0, false);
    d     = __builtin_amdgcn_cvt_pk_fp8_f32(v.z, v.w, d, true);
    return (uint32_t)d;
}

__device__ __forceinline__ float bfbits2f(unsigned short u) {
    union { uint32_t u; float f; } cv;
    cv.u = ((uint32_t)u) << 16;
    return cv.f;
}

__device__ __forceinline__ void gload_lds16(const void* g, void* l) {
    __builtin_amdgcn_global_load_lds(
        (const __attribute__((address_space(1))) void*)g,
        (__attribute__((address_space(3))) void*)l, 16, 0, 0);
}

__device__ __forceinline__ float sq16(const float4& a, const float4& b,
                                      const float4& c, const float4& d) {
    return a.x*a.x + a.y*a.y + a.z*a.z + a.w*a.w
         + b.x*b.x + b.y*b.y + b.z*b.z + b.w*b.w
         + c.x*c.x + c.y*c.y + c.z*c.z + c.w*c.w
         + d.x*d.x + d.y*d.y + d.z*d.z + d.w*d.w;
}

// ---------------------------------------------------------------------------
// prepass: c fp32 -> fp8 e4m3 (padded to 224 rows, zeros) + ||c||^2 halves.
__global__ __launch_bounds__(256) void rbf_prep(
    const float* __restrict__ c, uint8_t* __restrict__ cf8,
    float* __restrict__ ccp)
{
    __shared__ float red[4];
    const int j = blockIdx.x >> 1, h = blockIdx.x & 1;
    const int t = threadIdx.x;
    const int base = h * (D_SZ / 2);
    uint8_t* dst = cf8 + (size_t)j * D_SZ + base;
    float s = 0.f;
    if (j < M_SZ) {
        const float* src = c + (size_t)j * D_SZ + base;
        for (int i = t * 8; i < D_SZ / 2; i += 2048) {
            float4 v0 = *(const float4*)(src + i);
            float4 v1 = *(const float4*)(src + i + 4);
            s += v0.x*v0.x + v0.y*v0.y + v0.z*v0.z + v0.w*v0.w
               + v1.x*v1.x + v1.y*v1.y + v1.z*v1.z + v1.w*v1.w;
            uint2 w = { pk8x4(v0), pk8x4(v1) };
            *(uint2*)(dst + i) = w;
        }
    } else {
        uint2 zz = {0u, 0u};
        for (int i = t * 8; i < D_SZ / 2; i += 2048) *(uint2*)(dst + i) = zz;
    }
#pragma unroll
    for (int off = 32; off > 0; off >>= 1) s += __shfl_down(s, off);
    if ((t & 63) == 0) red[t >> 6] = s;
    __syncthreads();
    if (t == 0) ccp[j * 2 + h] = red[0] + red[1] + red[2] + red[3];
}

// ---------------------------------------------------------------------------
// main: split-K distance GEMM, 16x16x32 fp8_fp8 MFMA, BT=32, 4 blocks/CU.
// R9 structure with software-pipelined x loads: iter it+1's x floats are
// issued after the first barrier of iter it (fly during the MFMA window)
// and packed after the second barrier. Last-iteration trailing barrier peeled.
__global__ __launch_bounds__(256, 4) void rbf_main(
    const float* __restrict__ x, const uint8_t* __restrict__ cf8,
    __hip_bfloat16* __restrict__ slab, float* __restrict__ xxp)
{
    __shared__ uint8_t sx[BT * BK];     //  4 KB
    __shared__ uint8_t sc[MPAD * BK];   // 28 KB  (32 KB total -> 4 blocks/CU)

    const int t    = threadIdx.x;
    const int k    = blockIdx.x;
    const int b    = blockIdx.y;
    const int wave = t >> 6, lane = t & 63;
    const int quad = lane >> 4, mrow = lane & 15;
    const int qh = quad >> 1, ql = quad & 1;
    const int s2 = (mrow >> 1) & 7;
    const int rt  = wave & 1;           // row-tile (16 rows)
    const int cth = wave >> 1;          // ct-half (7 tiles)

    floatx4 acc[NCT];
    const floatx4 z4 = {0.f, 0.f, 0.f, 0.f};
#pragma unroll
    for (int i = 0; i < NCT; ++i) acc[i] = z4;

    // ---- c-DMA lane source pointers (R8/R9-verified mapping).
    const int oE = (((lane & 7) ^ (lane >> 4)) & 7) * 16;
    const int oO = ((((lane & 7) ^ (lane >> 4)) ^ 4) & 7) * 16;
    const uint8_t* cpbE = cf8 + (size_t)(lane >> 3) * D_SZ + (size_t)k * KCH + oE;
    const uint8_t* cpbO = cf8 + (size_t)(lane >> 3) * D_SZ + (size_t)k * KCH + oO;

    // ---- peel: issue iter-0 c-DMA before x-prefetch (flights overlap)
#pragma unroll
    for (int jj = 0; jj < 7; ++jj) {
        const int cr = wave * 7 + jj;
        const uint8_t* p = ((cr & 1) ? cpbO : cpbE) + (size_t)cr * 8 * D_SZ;
        gload_lds16(p, &sc[cr * 1024]);
    }

    // ---- x mapping: 8 threads/row, 16 floats each per iter
    const int xr = t >> 3;              // staging row 0..31
    const int xc = t & 7;               // 16-float column group
    const float* xp = x + (size_t)(b * BT + xr) * D_SZ + (size_t)k * KCH + xc * 16;

    // iter-0 x load + pack only (rest pipelined into the K-loop)
    float sxx = 0.f;
    uint4 xwcur;
    {
        float4 v0 = *(const float4*)(xp + 0);
        float4 v1 = *(const float4*)(xp + 4);
        float4 v2 = *(const float4*)(xp + 8);
        float4 v3 = *(const float4*)(xp + 12);
        sxx += sq16(v0, v1, v2, v3);
        xwcur = make_uint4(pk8x4(v0), pk8x4(v1), pk8x4(v2), pk8x4(v3));
    }
    // sx dest: row xr, chunk16 = xc ^ ((xr>>1)&7)
    uint8_t* sxw = &sx[xr * BK + ((xc ^ ((xr >> 1) & 7)) & 7) * 16];

    // ---- fragment offsets (shared by A and B; rows have same s2 law)
    int boff[4];
#pragma unroll
    for (int ks = 0; ks < 4; ++ks)
        boff[ks] = (((ks * 2 + qh) ^ s2) & 7) * 16 + ql * 8;
    const uint8_t* abase = &sx[(rt * 16 + mrow) * BK];
    const uint8_t* bbase = &sc[(cth * 7 * 16 + mrow) * BK];

#pragma unroll
    for (int it = 0; it < NIT; ++it) {
        *(uint4*)sxw = xwcur;
        __syncthreads();   // DMA(it) + x-writes complete

        // issue next iter's x loads now — they fly during the MFMA window
        float4 n0, n1, n2, n3;
        if (it + 1 < NIT) {
            const float* np = xp + (it + 1) * BK;
            n0 = *(const float4*)(np + 0);
            n1 = *(const float4*)(np + 4);
            n2 = *(const float4*)(np + 8);
            n3 = *(const float4*)(np + 12);
        }

#pragma unroll
        for (int ks = 0; ks < 4; ++ks) {
            const long a = *(const long*)(abase + boff[ks]);
#pragma unroll
            for (int ct = 0; ct < NCT; ++ct) {
                const long bv = *(const long*)(bbase + ct * 16 * BK + boff[ks]);
                acc[ct] = __builtin_amdgcn_mfma_f32_16x16x32_fp8_fp8(a, bv, acc[ct], 0, 0, 0);
            }
        }

        if (it + 1 < NIT) {
            __syncthreads();   // all reads of sx/sc done
            // issue next c-DMA immediately, then pack x behind it
#pragma unroll
            for (int jj = 0; jj < 7; ++jj) {
                const int cr = wave * 7 + jj;
                const uint8_t* p = ((cr & 1) ? cpbO : cpbE)
                                 + (size_t)cr * 8 * D_SZ + (it + 1) * BK;
                gload_lds16(p, &sc[cr * 1024]);
            }
            sxx += sq16(n0, n1, n2, n3);
            xwcur = make_uint4(pk8x4(n0), pk8x4(n1), pk8x4(n2), pk8x4(n3));
        }
        // last iteration: no trailing barrier (epilogue reads registers only)
    }

    // ---- slab write: [i][k][224] bf16. C/D: col=lane&15, row=quad*4+reg
    __hip_bfloat16* sd = slab + (size_t)k * SROW;
    const int gi0 = b * BT + rt * 16 + quad * 4;
#pragma unroll
    for (int ct = 0; ct < NCT; ++ct) {
        const int gj = (cth * NCT + ct) * 16 + mrow;
#pragma unroll
        for (int rg = 0; rg < 4; ++rg)
            sd[(size_t)(gi0 + rg) * SLROW + gj] = __float2bfloat16(acc[ct][rg]);
    }

    // ---- xx partials: 8 staging threads per row -> 1 write (no atomics)
    sxx += __shfl_down(sxx, 4);
    sxx += __shfl_down(sxx, 2);
    sxx += __shfl_down(sxx, 1);
    if ((t & 7) == 0) xxp[(size_t)(b * BT + xr) * KC + k] = sxx;
}

// ---------------------------------------------------------------------------
// finalize: one block per row; octet k-reduction of bf16 slab, then radial
// + W epilogue.
__global__ __launch_bounds__(256) void rbf_fin(
    const __hip_bfloat16* __restrict__ slab, const float* __restrict__ xxp,
    const float* __restrict__ ccp, const float* __restrict__ sigma,
    const float* __restrict__ W, const float* __restrict__ bias,
    float* __restrict__ out)
{
    __shared__ float jpart[MPAD * 9];
    __shared__ float jtot[MPAD];
    __shared__ float xsh;

    const int t = threadIdx.x;
    const int i = blockIdx.x;

    if (t < 64) {
        float xv = (t < KC) ? xxp[(size_t)i * KC + t] : 0.f;
#pragma unroll
        for (int off = 32; off > 0; off >>= 1) xv += __shfl_down(xv, off);
        if (t == 0) xsh = xv;
    }

    const int o = t % 28, g = t / 28;
    if (t < 252) {
        const unsigned short* sp = (const unsigned short*)slab
                                 + (size_t)i * SLROW + o * 8;
        float s8[8] = {0.f,0.f,0.f,0.f,0.f,0.f,0.f,0.f};
        for (int kk = g; kk < KC; kk += 9) {
            short8 v = *(const short8*)(sp + kk * SROW);
#pragma unroll
            for (int e = 0; e < 8; ++e) s8[e] += bfbits2f((unsigned short)v[e]);
        }
#pragma unroll
        for (int e = 0; e < 8; ++e) jpart[(o * 8 + e) * 9 + g] = s8[e];
    }
    __syncthreads();

    if (t < MPAD) {
        float d = 0.f;
#pragma unroll
        for (int g2 = 0; g2 < 9; ++g2) d += jpart[t * 9 + g2];
        jtot[t] = d;
    }
    __syncthreads();

    if (t < 64) {
        const float xxi = xsh;
        float a0 = 0.f, a1 = 0.f;
        for (int j = t; j < M_SZ; j += 64) {
            const float ccj = ccp[j * 2] + ccp[j * 2 + 1];
            float d2 = fmaxf(xxi + ccj - 2.f * jtot[j], 0.f);
            float sg = sigma[j];
            float rad = __expf(-sqrtf(d2) / (sg * sg));
            a0 += rad * W[j];
            a1 += rad * W[M_SZ + j];
        }
#pragma unroll
        for (int off = 32; off > 0; off >>= 1) {
            a0 += __shfl_down(a0, off);
            a1 += __shfl_down(a1, off);
        }
        if (t == 0) {
            out[i * 2 + 0] = a0 + bias[0];
            out[i * 2 + 1] = a1 + bias[1];
        }
    }
}

// ---------------------------------------------------------------------------
extern "C" void kernel_launch(void* const* d_in, const int* in_sizes, int n_in,
                              void* d_out, int out_size, void* d_ws, size_t ws_size,
                              hipStream_t stream)
{
    const float* x     = (const float*)d_in[0];
    const float* c     = (const float*)d_in[1];
    const float* sigma = (const float*)d_in[2];
    const float* W     = (const float*)d_in[3];
    const float* bias  = (const float*)d_in[4];
    float* out = (float*)d_out;

    char* ws = (char*)d_ws;
    uint8_t*        cf8  = (uint8_t*)(ws + CBF_OFF);
    float*          xxp  = (float*)(ws + XXP_OFF);
    float*          ccp  = (float*)(ws + CCP_OFF);
    __hip_bfloat16* slab = (__hip_bfloat16*)(ws + SLAB_OFF);

    rbf_prep<<<MPAD * 2, 256, 0, stream>>>(c, cf8, ccp);
    rbf_main<<<dim3(KC, NB), 256, 0, stream>>>(x, cf8, slab, xxp);
    rbf_fin<<<B_SZ, 256, 0, stream>>>(slab, xxp, ccp, sigma, W, bias, out);
}